// Round 8
// baseline (119.961 us; speedup 1.0000x reference)
//
#include <hip/hip_runtime.h>
#include <hip/hip_bf16.h>

#define IN_DIM  512
#define OUT_DIM 512
#define BATCH   4096
#define KDIM    4608            // permuted: k' = i*8+j (j=0..7 splines), 4096+i = silu
#define SPLITK  6
#define KSPLIT  768
#define NSTEPS  12              // KSPLIT / 64

// ws layout (bytes)
#define WOFF_WBF  0
#define WSZ_WBF   (OUT_DIM * KDIM * 2)                  // 4,718,592 (permuted bf16 W)
#define WOFF_PART (WOFF_WBF + WSZ_WBF)
#define WSZ_PART  (SPLITK * BATCH * OUT_DIM * 2)        // 25,165,824 (fp16 partials)
#define WOFF_TBL  (WOFF_PART + WSZ_PART)                // 512 float2 = 4 KB

typedef __attribute__((ext_vector_type(8))) short bf16x8;
typedef __attribute__((ext_vector_type(4))) float f32x4;
typedef __attribute__((ext_vector_type(8))) _Float16 h16x8;

__device__ __forceinline__ unsigned long long pack4(float a, float b, float c, float d) {
    __hip_bfloat16 ha = __float2bfloat16(a), hb = __float2bfloat16(b),
                   hc = __float2bfloat16(c), hd = __float2bfloat16(d);
    return  (unsigned long long)*reinterpret_cast<unsigned short*>(&ha)
         | ((unsigned long long)*reinterpret_cast<unsigned short*>(&hb) << 16)
         | ((unsigned long long)*reinterpret_cast<unsigned short*>(&hc) << 32)
         | ((unsigned long long)*reinterpret_cast<unsigned short*>(&hd) << 48);
}

__device__ __forceinline__ float silux(float z) {     // silu(z)*z
    return z * z / (1.0f + __expf(-z));
}

// one spline eval -> 8-basis bf16 fragment (bases j=mi..mi+3 nonzero, placed
// by 128-bit funnel shift; identical math to the verified round-6 kernel)
__device__ __forceinline__ bf16x8 spline_frag(float xv, float2 t) {
    float ss = (xv - t.x) * t.y;                      // in [0,5)
    int mi = (int)ss; mi = mi < 0 ? 0 : (mi > 4 ? 4 : mi);
    float u  = ss - (float)mi;
    float u2 = u * u, u3 = u2 * u;
    float om = 1.0f - u;
    float xb = xv * (1.0f / 6.0f);
    float b0 = om * om * om * xb;
    float b1 = (3.0f * u3 - 6.0f * u2 + 4.0f) * xb;
    float b2 = (-3.0f * u3 + 3.0f * u2 + 3.0f * u + 1.0f) * xb;
    float b3 = u3 * xb;
    unsigned long long p = pack4(b0, b1, b2, b3);
    unsigned sh = (unsigned)mi << 4;                  // 0,16,32,48,64
    unsigned long long l1 = p << (sh & 63);
    unsigned long long r1 = p >> ((64u - sh) & 63);
    unsigned long long lo = (sh == 64u) ? 0ull : l1;
    unsigned long long hi = (sh == 0u)  ? 0ull : ((sh == 64u) ? p : r1);
    union { unsigned long long q[2]; bf16x8 f; } u_;
    u_.q[0] = lo; u_.q[1] = hi;
    return u_.f;
}

__device__ __forceinline__ bf16x8 silu_frag(const float* __restrict__ xp) {
    float4 a = *reinterpret_cast<const float4*>(xp);
    float4 b = *reinterpret_cast<const float4*>(xp + 4);
    union { unsigned long long q[2]; bf16x8 f; } u_;
    u_.q[0] = pack4(silux(a.x), silux(a.y), silux(a.z), silux(a.w));
    u_.q[1] = pack4(silux(b.x), silux(b.y), silux(b.z), silux(b.w));
    return u_.f;
}

// ---------------- K1: weight cast + K-permute, plus grid table ----------------
__global__ __launch_bounds__(256) void cast_w_perm(const float* __restrict__ w,
                                                   short* __restrict__ wp,
                                                   const float* __restrict__ grid,
                                                   float2* __restrict__ tbl) {
    int blk = blockIdx.x;
    if (blk == 1024) {                                  // grid table
        for (int i = threadIdx.x; i < IN_DIM; i += 256) {
            float g0 = grid[i * 6];
            float g5 = grid[i * 6 + 5];
            tbl[i] = make_float2(g0, 5.0f / (g5 - g0));
        }
        return;
    }
    int idx = blk * 256 + threadIdx.x;                  // (o,i)
    int o = idx >> 9;
    int i = idx & 511;
    const float* wo = w + (size_t)o * KDIM;
    bf16x8 v;
#pragma unroll
    for (int j = 0; j < 8; ++j) {
        __hip_bfloat16 h = __float2bfloat16(wo[j * 512 + i]);
        v[j] = *reinterpret_cast<short*>(&h);
    }
    *reinterpret_cast<bf16x8*>(wp + (size_t)o * KDIM + i * 8) = v;
    __hip_bfloat16 h8 = __float2bfloat16(wo[8 * 512 + i]);
    wp[(size_t)o * KDIM + 4096 + i] = *reinterpret_cast<short*>(&h8);
}

// ---------------- K2: fused GEMM, A-fragments evaluated in registers ----------
// 256 threads = 4 waves (2x2), BM=BN=128, BK=64, split-K=6, grid=768 (3/CU).
// No A LDS tile: each lane evaluates its own af (row = wr*64+m*16+(lane&15),
// i = k0g/8 + ks*4 + (lane>>4)) straight into registers.
#define BM 128
#define BN 128
#define BK 64

__global__ __launch_bounds__(256) void gemm_fused(const float* __restrict__ x,
                                                  const short* __restrict__ Wp,
                                                  const float2* __restrict__ tbl,
                                                  _Float16* __restrict__ part) {
    __shared__ __align__(16) short Ws[BN * BK];       // 16 KB, XOR-swizzled 16B slots

    // XCD swizzle (bijective: 768 = 8*96), sk-major so each XCD's W-slice
    // (512x768x2B = 786 KB) and x-slice stay L2-resident.
    int l  = (blockIdx.x & 7) * 96 + (blockIdx.x >> 3);
    int sk = l >> 7;              // 0..5
    int bm = (l & 127) >> 2;      // 0..31
    int bn = l & 3;               // 0..3

    int tid  = threadIdx.x;
    int lane = tid & 63;
    int wid  = tid >> 6;          // 0..3
    int wr   = wid >> 1;          // 0..1
    int wc   = wid & 1;           // 0..1
    int g    = lane >> 4;         // 0..3 (k-octet)
    int fr   = lane & 15;

    const short* Wb = Wp + (size_t)(bn * BN) * KDIM + sk * KSPLIT;
    int srow = lane >> 3;
    int scol = ((lane & 7) ^ srow) * 8;   // inverse-swizzled global source

    f32x4 acc[4][4];
#pragma unroll
    for (int m = 0; m < 4; ++m)
#pragma unroll
        for (int n = 0; n < 4; ++n) acc[m][n] = (f32x4){0.f, 0.f, 0.f, 0.f};

    int row0 = bm * BM + wr * 64 + fr;    // + m*16

    for (int kb = 0; kb < NSTEPS; ++kb) {
        int k0l = kb * BK;
        int k0g = sk * KSPLIT + k0l;
        __syncthreads();                  // prev step's Ws readers done

        // issue async W staging (4 x 32 rows; wave-uniform LDS base)
#pragma unroll
        for (int i = 0; i < 4; ++i) {
            int r0 = i * 32 + wid * 8;
            __builtin_amdgcn_global_load_lds(
                (const __attribute__((address_space(1))) void*)(Wb + (size_t)(r0 + srow) * KDIM + k0l + scol),
                (__attribute__((address_space(3))) void*)(&Ws[r0 * 64]),
                16, 0, 0);
        }

        // evaluate A fragments in registers (covers the W-load latency)
        bf16x8 af[4][2];
        if (k0g < 4096) {                 // spline region (wave-uniform branch)
            int i0 = k0g >> 3;
#pragma unroll
            for (int ks = 0; ks < 2; ++ks) {
                int i = i0 + ks * 4 + g;
                float2 t = tbl[i];
#pragma unroll
                for (int m = 0; m < 4; ++m)
                    af[m][ks] = spline_frag(x[(size_t)(row0 + m * 16) * IN_DIM + i], t);
            }
        } else {                          // silu region
            int ib = k0g - 4096;
#pragma unroll
            for (int ks = 0; ks < 2; ++ks)
#pragma unroll
                for (int m = 0; m < 4; ++m)
                    af[m][ks] = silu_frag(&x[(size_t)(row0 + m * 16) * IN_DIM + ib + ks * 32 + g * 8]);
        }

        __syncthreads();                  // vmcnt drain: Ws ready

#pragma unroll
        for (int ks = 0; ks < 2; ++ks) {
            int kk8 = ks * 4 + g;
            bf16x8 wf[4];
#pragma unroll
            for (int n = 0; n < 4; ++n) {
                int col = wc * 64 + n * 16 + fr;
                int slot = kk8 ^ (col & 7);
                wf[n] = *reinterpret_cast<const bf16x8*>(&Ws[col * 64 + slot * 8]);
            }
#pragma unroll
            for (int m = 0; m < 4; ++m)
#pragma unroll
                for (int n = 0; n < 4; ++n)
                    acc[m][n] = __builtin_amdgcn_mfma_f32_16x16x32_bf16(af[m][ks], wf[n], acc[m][n], 0, 0, 0);
        }
    }

    // epilogue: C/D col = lane&15, row = (lane>>4)*4 + reg; fp16 partials
    _Float16* p = part + (size_t)sk * BATCH * OUT_DIM;
    int crow0 = bm * BM + wr * 64 + (lane >> 4) * 4;
    int ccol0 = bn * BN + wc * 64 + fr;
#pragma unroll
    for (int m = 0; m < 4; ++m)
#pragma unroll
        for (int n = 0; n < 4; ++n)
#pragma unroll
            for (int r = 0; r < 4; ++r)
                p[(size_t)(crow0 + m * 16 + r) * OUT_DIM + ccol0 + n * 16] =
                    (_Float16)acc[m][n][r];
}

// ---------------- K3: reduce fp16 partials + bias ----------------
__global__ __launch_bounds__(256) void reduce_out(const _Float16* __restrict__ part,
                                                  const float4* __restrict__ bias,
                                                  float4* __restrict__ out) {
    int idx = blockIdx.x * 256 + threadIdx.x;     // 8 outputs each
    const size_t stride = (size_t)BATCH * OUT_DIM;
    float4 b0 = bias[(idx & 63) * 2];
    float4 b1 = bias[(idx & 63) * 2 + 1];
    float a[8] = {b0.x, b0.y, b0.z, b0.w, b1.x, b1.y, b1.z, b1.w};
#pragma unroll
    for (int s = 0; s < SPLITK; ++s) {
        h16x8 v = *reinterpret_cast<const h16x8*>(part + (size_t)s * stride + (size_t)idx * 8);
#pragma unroll
        for (int j = 0; j < 8; ++j) a[j] += (float)v[j];
    }
    out[idx * 2]     = (float4){a[0], a[1], a[2], a[3]};
    out[idx * 2 + 1] = (float4){a[4], a[5], a[6], a[7]};
}

extern "C" void kernel_launch(void* const* d_in, const int* in_sizes, int n_in,
                              void* d_out, int out_size, void* d_ws, size_t ws_size,
                              hipStream_t stream) {
    (void)in_sizes; (void)n_in; (void)out_size; (void)ws_size;
    const float* x      = (const float*)d_in[0];
    const float* grid   = (const float*)d_in[1];
    const float* weight = (const float*)d_in[2];
    const float* bias   = (const float*)d_in[3];

    char* ws = (char*)d_ws;
    short*    wbf  = (short*)(ws + WOFF_WBF);
    _Float16* part = (_Float16*)(ws + WOFF_PART);
    float2*   tbl  = (float2*)(ws + WOFF_TBL);

    cast_w_perm<<<1025, 256, 0, stream>>>(weight, wbf, grid, tbl);
    gemm_fused<<<768, 256, 0, stream>>>(x, wbf, tbl, part);
    reduce_out<<<(BATCH * OUT_DIM / 8) / 256, 256, 0, stream>>>(
        part, (const float4*)bias, (float4*)d_out);
}

// Round 9
// 76.610 us; speedup vs baseline: 1.5659x; 1.5659x over previous
//
#include <hip/hip_runtime.h>
#include <hip/hip_bf16.h>

#define IN_DIM  512
#define OUT_DIM 512
#define BATCH   4096
#define KDIM    4608            // permuted: k' = i*8+j (j=0..7 splines), 4096+i = silu
#define SPLITK  6
#define KSPLIT  768             // KDIM / SPLITK
#define NSTEPS  12              // KSPLIT / 64

// ws layout (bytes)
#define WOFF_WBF  0
#define WSZ_WBF   (OUT_DIM * KDIM * 2)                  // 4,718,592 (permuted bf16 W)
#define WOFF_PART (WOFF_WBF + WSZ_WBF)
#define WSZ_PART  (SPLITK * BATCH * OUT_DIM * 2)        // 25,165,824 (fp16 partials)
#define WOFF_TBL  (WOFF_PART + WSZ_PART)                // 512 float2 = 4 KB

typedef __attribute__((ext_vector_type(8))) short bf16x8;
typedef __attribute__((ext_vector_type(4))) float f32x4;
typedef __attribute__((ext_vector_type(8))) _Float16 h16x8;

__device__ __forceinline__ unsigned long long pack4(float a, float b, float c, float d) {
    __hip_bfloat16 ha = __float2bfloat16(a), hb = __float2bfloat16(b),
                   hc = __float2bfloat16(c), hd = __float2bfloat16(d);
    return  (unsigned long long)*reinterpret_cast<unsigned short*>(&ha)
         | ((unsigned long long)*reinterpret_cast<unsigned short*>(&hb) << 16)
         | ((unsigned long long)*reinterpret_cast<unsigned short*>(&hc) << 32)
         | ((unsigned long long)*reinterpret_cast<unsigned short*>(&hd) << 48);
}

__device__ __forceinline__ float silux(float z) {     // silu(z)*z
    return z * z / (1.0f + __expf(-z));
}

// one spline eval -> 8-basis bf16 fragment (bases mi..mi+3 nonzero, placed by
// 128-bit funnel shift; identical math to the verified round-4/6 kernels)
__device__ __forceinline__ bf16x8 spline_frag(float xv, float2 t) {
    float ss = (xv - t.x) * t.y;                      // in [0,5)
    int mi = (int)ss; mi = mi < 0 ? 0 : (mi > 4 ? 4 : mi);
    float u  = ss - (float)mi;
    float u2 = u * u, u3 = u2 * u;
    float om = 1.0f - u;
    float xb = xv * (1.0f / 6.0f);
    float b0 = om * om * om * xb;
    float b1 = (3.0f * u3 - 6.0f * u2 + 4.0f) * xb;
    float b2 = (-3.0f * u3 + 3.0f * u2 + 3.0f * u + 1.0f) * xb;
    float b3 = u3 * xb;
    unsigned long long p = pack4(b0, b1, b2, b3);
    unsigned sh = (unsigned)mi << 4;                  // 0,16,32,48,64
    unsigned long long l1 = p << (sh & 63);
    unsigned long long r1 = p >> ((64u - sh) & 63);
    unsigned long long lo = (sh == 64u) ? 0ull : l1;
    unsigned long long hi = (sh == 0u)  ? 0ull : ((sh == 64u) ? p : r1);
    union { unsigned long long q[2]; bf16x8 f; } u_;
    u_.q[0] = lo; u_.q[1] = hi;
    return u_.f;
}

// ---------------- K1: weight cast + K-permute, plus grid table ----------------
__global__ __launch_bounds__(256) void cast_w_perm(const float* __restrict__ w,
                                                   short* __restrict__ wp,
                                                   const float* __restrict__ grid,
                                                   float2* __restrict__ tbl) {
    int blk = blockIdx.x;
    if (blk == 1024) {                                  // grid table
        for (int i = threadIdx.x; i < IN_DIM; i += 256) {
            float g0 = grid[i * 6];
            float g5 = grid[i * 6 + 5];
            tbl[i] = make_float2(g0, 5.0f / (g5 - g0));
        }
        return;
    }
    int idx = blk * 256 + threadIdx.x;                  // (o,i)
    int o = idx >> 9;
    int i = idx & 511;
    const float* wo = w + (size_t)o * KDIM;
    bf16x8 v;
#pragma unroll
    for (int j = 0; j < 8; ++j) {
        __hip_bfloat16 h = __float2bfloat16(wo[j * 512 + i]);
        v[j] = *reinterpret_cast<short*>(&h);
    }
    *reinterpret_cast<bf16x8*>(wp + (size_t)o * KDIM + i * 8) = v;
    __hip_bfloat16 h8 = __float2bfloat16(wo[8 * 512 + i]);
    wp[(size_t)o * KDIM + 4096 + i] = *reinterpret_cast<short*>(&h8);
}

// ---------------- K2: fused acts+GEMM, m97 structure, 3 blocks/CU ----------
// 256 threads = 4 waves (2x2), BM=BN=128, BK=64, split-K=6, grid=768 (3/CU),
// 32 KB LDS single-buffered, 2-barrier K-loop. A built in LDS from coalesced
// float4 x-loads (4 evals/thread/step); W via async global_load_lds.
#define BM 128
#define BN 128
#define BK 64

__global__ __launch_bounds__(256) void gemm_fused(const float* __restrict__ x,
                                                  const short* __restrict__ Wp,
                                                  const float2* __restrict__ tbl,
                                                  _Float16* __restrict__ part) {
    __shared__ __align__(16) short As[BM * BK];       // 16 KB, XOR-swizzled 16B slots
    __shared__ __align__(16) short Ws[BN * BK];       // 16 KB

    // XCD swizzle (bijective: 768 = 8*96); consecutive logical ids share the
    // A-panel (bn minor) and one sk's W-slice (786 KB) -> L2-resident per XCD.
    int l  = (blockIdx.x & 7) * 96 + (blockIdx.x >> 3);
    int sk = l >> 7;              // 0..5
    int bm = (l & 127) >> 2;      // 0..31
    int bn = l & 3;               // 0..3

    int tid  = threadIdx.x;
    int lane = tid & 63;
    int wid  = tid >> 6;          // 0..3
    int wr   = wid >> 1;          // 0..1
    int wc   = wid & 1;           // 0..1
    int g    = lane >> 4;         // 0..3 (k-octet)
    int fr   = lane & 15;

    const short* Wb = Wp + (size_t)(bn * BN) * KDIM + sk * KSPLIT;
    int srow = lane >> 3;
    int scol = ((lane & 7) ^ srow) * 8;   // inverse-swizzled global source

    // A build: thread owns row arow = tid>>1, col8 slots {t*4 .. t*4+3}, t=tid&1.
    // x read = one float4 (coalesced); write slot = col8 ^ (arow&7) -> 2 lanes/bank.
    int arow = tid >> 1;
    int t4   = (tid & 1) * 4;
    int r7   = arow & 7;
    const float* xrow = x + (size_t)(bm * BM + arow) * IN_DIM;

    f32x4 acc[4][4];
#pragma unroll
    for (int m = 0; m < 4; ++m)
#pragma unroll
        for (int n = 0; n < 4; ++n) acc[m][n] = (f32x4){0.f, 0.f, 0.f, 0.f};

    for (int kb = 0; kb < NSTEPS; ++kb) {
        int k0l = kb * BK;
        int k0g = sk * KSPLIT + k0l;
        __syncthreads();                  // prev step's LDS readers done

        // issue async W staging first (latency hides under A-eval VALU)
#pragma unroll
        for (int i = 0; i < 4; ++i) {
            int r0 = i * 32 + wid * 8;
            __builtin_amdgcn_global_load_lds(
                (const __attribute__((address_space(1))) void*)(Wb + (size_t)(r0 + srow) * KDIM + k0l + scol),
                (__attribute__((address_space(3))) void*)(&Ws[r0 * 64]),
                16, 0, 0);
        }

        // build A tile in LDS (4 x 16B slots per thread)
        if (k0g < 4096) {                 // spline region (step-uniform branch)
            int ibase = (k0g >> 3) + t4;
            float4 xv = *reinterpret_cast<const float4*>(&xrow[ibase]);
            float2 tb0 = tbl[ibase], tb1 = tbl[ibase + 1],
                   tb2 = tbl[ibase + 2], tb3 = tbl[ibase + 3];
            bf16x8 f0 = spline_frag(xv.x, tb0);
            bf16x8 f1 = spline_frag(xv.y, tb1);
            bf16x8 f2 = spline_frag(xv.z, tb2);
            bf16x8 f3 = spline_frag(xv.w, tb3);
            *reinterpret_cast<bf16x8*>(&As[arow * 64 + ((t4 + 0) ^ r7) * 8]) = f0;
            *reinterpret_cast<bf16x8*>(&As[arow * 64 + ((t4 + 1) ^ r7) * 8]) = f1;
            *reinterpret_cast<bf16x8*>(&As[arow * 64 + ((t4 + 2) ^ r7) * 8]) = f2;
            *reinterpret_cast<bf16x8*>(&As[arow * 64 + ((t4 + 3) ^ r7) * 8]) = f3;
        } else {                          // silu region: k' = 4096 + i
            int ib = k0g - 4096 + t4 * 8;
#pragma unroll
            for (int c = 0; c < 4; ++c) {
                float4 a = *reinterpret_cast<const float4*>(&xrow[ib + c * 8]);
                float4 b = *reinterpret_cast<const float4*>(&xrow[ib + c * 8 + 4]);
                union { unsigned long long q[2]; bf16x8 f; } u_;
                u_.q[0] = pack4(silux(a.x), silux(a.y), silux(a.z), silux(a.w));
                u_.q[1] = pack4(silux(b.x), silux(b.y), silux(b.z), silux(b.w));
                *reinterpret_cast<bf16x8*>(&As[arow * 64 + ((t4 + c) ^ r7) * 8]) = u_.f;
            }
        }
        __syncthreads();                  // vmcnt + lgkm drain: tiles ready

#pragma unroll
        for (int ks = 0; ks < 2; ++ks) {
            int kk8 = ks * 4 + g;
            bf16x8 af[4], wf[4];
#pragma unroll
            for (int m = 0; m < 4; ++m) {
                int row = wr * 64 + m * 16 + fr;
                int slot = kk8 ^ (row & 7);
                af[m] = *reinterpret_cast<const bf16x8*>(&As[row * 64 + slot * 8]);
            }
#pragma unroll
            for (int n = 0; n < 4; ++n) {
                int col = wc * 64 + n * 16 + fr;
                int slot = kk8 ^ (col & 7);
                wf[n] = *reinterpret_cast<const bf16x8*>(&Ws[col * 64 + slot * 8]);
            }
#pragma unroll
            for (int m = 0; m < 4; ++m)
#pragma unroll
                for (int n = 0; n < 4; ++n)
                    acc[m][n] = __builtin_amdgcn_mfma_f32_16x16x32_bf16(af[m], wf[n], acc[m][n], 0, 0, 0);
        }
    }

    // epilogue: C/D col = lane&15, row = (lane>>4)*4 + reg; fp16 partials
    _Float16* p = part + (size_t)sk * BATCH * OUT_DIM;
    int crow0 = bm * BM + wr * 64 + (lane >> 4) * 4;
    int ccol0 = bn * BN + wc * 64 + fr;
#pragma unroll
    for (int m = 0; m < 4; ++m)
#pragma unroll
        for (int n = 0; n < 4; ++n)
#pragma unroll
            for (int r = 0; r < 4; ++r)
                p[(size_t)(crow0 + m * 16 + r) * OUT_DIM + ccol0 + n * 16] =
                    (_Float16)acc[m][n][r];
}

// ---------------- K3: reduce fp16 partials + bias ----------------
__global__ __launch_bounds__(256) void reduce_out(const _Float16* __restrict__ part,
                                                  const float4* __restrict__ bias,
                                                  float4* __restrict__ out) {
    int idx = blockIdx.x * 256 + threadIdx.x;     // 8 outputs each
    const size_t stride = (size_t)BATCH * OUT_DIM;
    float4 b0 = bias[(idx & 63) * 2];
    float4 b1 = bias[(idx & 63) * 2 + 1];
    float a[8] = {b0.x, b0.y, b0.z, b0.w, b1.x, b1.y, b1.z, b1.w};
#pragma unroll
    for (int s = 0; s < SPLITK; ++s) {
        h16x8 v = *reinterpret_cast<const h16x8*>(part + (size_t)s * stride + (size_t)idx * 8);
#pragma unroll
        for (int j = 0; j < 8; ++j) a[j] += (float)v[j];
    }
    out[idx * 2]     = (float4){a[0], a[1], a[2], a[3]};
    out[idx * 2 + 1] = (float4){a[4], a[5], a[6], a[7]};
}

extern "C" void kernel_launch(void* const* d_in, const int* in_sizes, int n_in,
                              void* d_out, int out_size, void* d_ws, size_t ws_size,
                              hipStream_t stream) {
    (void)in_sizes; (void)n_in; (void)out_size; (void)ws_size;
    const float* x      = (const float*)d_in[0];
    const float* grid   = (const float*)d_in[1];
    const float* weight = (const float*)d_in[2];
    const float* bias   = (const float*)d_in[3];

    char* ws = (char*)d_ws;
    short*    wbf  = (short*)(ws + WOFF_WBF);
    _Float16* part = (_Float16*)(ws + WOFF_PART);
    float2*   tbl  = (float2*)(ws + WOFF_TBL);

    cast_w_perm<<<1025, 256, 0, stream>>>(weight, wbf, grid, tbl);
    gemm_fused<<<768, 256, 0, stream>>>(x, wbf, tbl, part);
    reduce_out<<<(BATCH * OUT_DIM / 8) / 256, 256, 0, stream>>>(
        part, (const float4*)bias, (float4*)d_out);
}

// Round 10
// 57.141 us; speedup vs baseline: 2.0994x; 1.3407x over previous
//
#include <hip/hip_runtime.h>
#include <hip/hip_bf16.h>

#define IN_DIM  512
#define OUT_DIM 512
#define BATCH   4096
#define KDIM    4608            // permuted: k' = i*8+j (j=0..7 splines), 4096+i = silu
#define SPLITK  8
#define KSPLIT  576             // KDIM / SPLITK
#define NSTEPS  9               // KSPLIT / 64

// ws layout (bytes)
#define WOFF_WBF  0
#define WSZ_WBF   (OUT_DIM * KDIM * 2)                  // 4,718,592 (permuted bf16 W)
#define WOFF_ACTS (WOFF_WBF + WSZ_WBF)
#define WSZ_ACTS  (BATCH * KDIM * 2)                    // 37,748,736 (permuted bf16 acts)
#define WOFF_PART (WOFF_ACTS + WSZ_ACTS)
#define WSZ_PART  (SPLITK * BATCH * OUT_DIM * 2)        // 33,554,432 (fp16 partials)

typedef __attribute__((ext_vector_type(8))) short bf16x8;
typedef __attribute__((ext_vector_type(4))) float f32x4;
typedef __attribute__((ext_vector_type(8))) _Float16 h16x8;

__device__ __forceinline__ unsigned long long pack4(float a, float b, float c, float d) {
    __hip_bfloat16 ha = __float2bfloat16(a), hb = __float2bfloat16(b),
                   hc = __float2bfloat16(c), hd = __float2bfloat16(d);
    return  (unsigned long long)*reinterpret_cast<unsigned short*>(&ha)
         | ((unsigned long long)*reinterpret_cast<unsigned short*>(&hb) << 16)
         | ((unsigned long long)*reinterpret_cast<unsigned short*>(&hc) << 32)
         | ((unsigned long long)*reinterpret_cast<unsigned short*>(&hd) << 48);
}

__device__ __forceinline__ float silux(float z) {     // silu(z)*z
    return z * z / (1.0f + __expf(-z));
}

// one spline eval -> 8-basis bf16 fragment x-premultiplied (bases mi..mi+3
// nonzero, placed by 128-bit funnel shift; math verified rounds 4-9)
__device__ __forceinline__ bf16x8 spline_frag(float xv, float2 t) {
    float ss = (xv - t.x) * t.y;                      // in [0,5)
    int mi = (int)ss; mi = mi < 0 ? 0 : (mi > 4 ? 4 : mi);
    float u  = ss - (float)mi;
    float u2 = u * u, u3 = u2 * u;
    float om = 1.0f - u;
    float xb = xv * (1.0f / 6.0f);
    float b0 = om * om * om * xb;
    float b1 = (3.0f * u3 - 6.0f * u2 + 4.0f) * xb;
    float b2 = (-3.0f * u3 + 3.0f * u2 + 3.0f * u + 1.0f) * xb;
    float b3 = u3 * xb;
    unsigned long long p = pack4(b0, b1, b2, b3);
    unsigned sh = (unsigned)mi << 4;                  // 0,16,32,48,64
    unsigned long long l1 = p << (sh & 63);
    unsigned long long r1 = p >> ((64u - sh) & 63);
    unsigned long long lo = (sh == 64u) ? 0ull : l1;
    unsigned long long hi = (sh == 0u)  ? 0ull : ((sh == 64u) ? p : r1);
    union { unsigned long long q[2]; bf16x8 f; } u_;
    u_.q[0] = lo; u_.q[1] = hi;
    return u_.f;
}

// ---------------- K1: fused W cast+permute AND permuted-acts build ----------
// blocks [0,1024): wp[o][i*8+j] = bf16(w[o][j*512+i]), wp[o][4096+i] = bf16(w[o][8*512+i])
// blocks [1024,3072): acts[b][i*8+j] (16B stores) + acts[b][4096+i] (8B stores)
#define WCAST_BLOCKS 1024
__global__ __launch_bounds__(256) void prep2(const float* __restrict__ w,
                                             short* __restrict__ wp,
                                             const float* __restrict__ x,
                                             const float* __restrict__ grid,
                                             short* __restrict__ acts) {
    int blk = blockIdx.x;
    if (blk < WCAST_BLOCKS) {
        int idx = blk * 256 + threadIdx.x;              // (o,i)
        int o = idx >> 9;
        int i = idx & 511;
        const float* wo = w + (size_t)o * KDIM;
        bf16x8 v;
#pragma unroll
        for (int j = 0; j < 8; ++j) {
            __hip_bfloat16 h = __float2bfloat16(wo[j * 512 + i]);
            v[j] = *reinterpret_cast<short*>(&h);
        }
        *reinterpret_cast<bf16x8*>(wp + (size_t)o * KDIM + i * 8) = v;
        __hip_bfloat16 h8 = __float2bfloat16(wo[8 * 512 + i]);
        wp[(size_t)o * KDIM + 4096 + i] = *reinterpret_cast<short*>(&h8);
        return;
    }
    int idx = (blk - WCAST_BLOCKS) * 256 + threadIdx.x; // 0..524287; 4 i's each
    int b  = idx >> 7;
    int i0 = (idx & 127) * 4;
    float4 xv = *reinterpret_cast<const float4*>(&x[(size_t)b * IN_DIM + i0]);
    short* arow = acts + (size_t)b * KDIM;
    short4 sil;
#pragma unroll
    for (int c = 0; c < 4; ++c) {
        int i = i0 + c;
        float xc = (c == 0) ? xv.x : (c == 1) ? xv.y : (c == 2) ? xv.z : xv.w;
        float g0 = grid[i * 6];
        float g5 = grid[i * 6 + 5];
        float2 t = make_float2(g0, 5.0f / (g5 - g0));
        bf16x8 f = spline_frag(xc, t);
        *reinterpret_cast<bf16x8*>(&arow[i * 8]) = f;   // 16B coalesced
        __hip_bfloat16 hs = __float2bfloat16(silux(xc));
        ((short*)&sil)[c] = *reinterpret_cast<short*>(&hs);
    }
    *reinterpret_cast<short4*>(&arow[4096 + i0]) = sil; // 8B coalesced
}

// ---------------- K2: bf16 MFMA GEMM (m97 structure), split-K=8 -------------
// 256 thr = 4 waves (2x2), BM=BN=128, BK=64, grid 1024 = 4 blocks/CU.
#define BM 128
#define BN 128
#define BK 64

__global__ __launch_bounds__(256) void gemm_kan(const short* __restrict__ A,
                                                const short* __restrict__ W,
                                                _Float16* __restrict__ part) {
    __shared__ __align__(16) short As[BM * BK];    // 16 KB, XOR-swizzled 16B slots
    __shared__ __align__(16) short Ws[BN * BK];    // 16 KB

    // sk-major XCD swizzle (bijective: 1024 = 8*128): XCD x owns sk=x entirely
    // -> per-XCD W-slice 512x576x2B = 590 KB, L2-resident.
    int l  = (blockIdx.x & 7) * 128 + (blockIdx.x >> 3);
    int sk = l >> 7;              // 0..7
    int bm = (l & 127) >> 2;      // 0..31
    int bn = l & 3;               // 0..3

    int tid  = threadIdx.x;
    int lane = tid & 63;
    int wid  = tid >> 6;          // 0..3
    int wr   = wid >> 1;          // 0..1
    int wc   = wid & 1;           // 0..1

    const short* Ab = A + (size_t)(bm * BM) * KDIM + sk * KSPLIT;
    const short* Wb = W + (size_t)(bn * BN) * KDIM + sk * KSPLIT;

    f32x4 acc[4][4];
#pragma unroll
    for (int m = 0; m < 4; ++m)
#pragma unroll
        for (int n = 0; n < 4; ++n) acc[m][n] = (f32x4){0.f, 0.f, 0.f, 0.f};

    // staging: wave w covers rows r0+srow, slot lane&7; LDS slot s of row r
    // holds global col8 (s ^ (r&7)) -> source col8 = (lane&7) ^ srow (rule #21)
    int srow = lane >> 3;
    int scol = ((lane & 7) ^ srow) * 8;

    for (int kb = 0; kb < NSTEPS; ++kb) {
        int k0 = kb * BK;
        __syncthreads();
#pragma unroll
        for (int i = 0; i < 4; ++i) {           // A tile: 128 rows
            int r0 = i * 32 + wid * 8;
            __builtin_amdgcn_global_load_lds(
                (const __attribute__((address_space(1))) void*)(Ab + (size_t)(r0 + srow) * KDIM + k0 + scol),
                (__attribute__((address_space(3))) void*)(&As[r0 * 64]),
                16, 0, 0);
        }
#pragma unroll
        for (int i = 0; i < 4; ++i) {           // W tile: 128 rows
            int r0 = i * 32 + wid * 8;
            __builtin_amdgcn_global_load_lds(
                (const __attribute__((address_space(1))) void*)(Wb + (size_t)(r0 + srow) * KDIM + k0 + scol),
                (__attribute__((address_space(3))) void*)(&Ws[r0 * 64]),
                16, 0, 0);
        }
        __syncthreads();

        int g = lane >> 4;
        int fr = lane & 15;
#pragma unroll
        for (int ks = 0; ks < 2; ++ks) {
            int kk8 = ks * 4 + g;
            bf16x8 af[4], wf[4];
#pragma unroll
            for (int m = 0; m < 4; ++m) {
                int row = wr * 64 + m * 16 + fr;
                int slot = kk8 ^ (row & 7);
                af[m] = *reinterpret_cast<const bf16x8*>(&As[row * 64 + slot * 8]);
            }
#pragma unroll
            for (int n = 0; n < 4; ++n) {
                int col = wc * 64 + n * 16 + fr;
                int slot = kk8 ^ (col & 7);
                wf[n] = *reinterpret_cast<const bf16x8*>(&Ws[col * 64 + slot * 8]);
            }
#pragma unroll
            for (int m = 0; m < 4; ++m)
#pragma unroll
                for (int n = 0; n < 4; ++n)
                    acc[m][n] = __builtin_amdgcn_mfma_f32_16x16x32_bf16(af[m], wf[n], acc[m][n], 0, 0, 0);
        }
    }

    // epilogue: C/D col = lane&15, row = (lane>>4)*4 + reg; fp16 partials
    _Float16* p = part + (size_t)sk * BATCH * OUT_DIM;
    int crow0 = bm * BM + wr * 64 + (lane >> 4) * 4;
    int ccol0 = bn * BN + wc * 64 + (lane & 15);
#pragma unroll
    for (int m = 0; m < 4; ++m)
#pragma unroll
        for (int n = 0; n < 4; ++n)
#pragma unroll
            for (int r = 0; r < 4; ++r)
                p[(size_t)(crow0 + m * 16 + r) * OUT_DIM + ccol0 + n * 16] =
                    (_Float16)acc[m][n][r];
}

// ---------------- K3: reduce fp16 partials + bias ----------------
__global__ __launch_bounds__(256) void reduce_out(const _Float16* __restrict__ part,
                                                  const float4* __restrict__ bias,
                                                  float4* __restrict__ out) {
    int idx = blockIdx.x * 256 + threadIdx.x;     // 8 outputs each
    const size_t stride = (size_t)BATCH * OUT_DIM;
    float4 b0 = bias[(idx & 63) * 2];
    float4 b1 = bias[(idx & 63) * 2 + 1];
    float a[8] = {b0.x, b0.y, b0.z, b0.w, b1.x, b1.y, b1.z, b1.w};
#pragma unroll
    for (int s = 0; s < SPLITK; ++s) {
        h16x8 v = *reinterpret_cast<const h16x8*>(part + (size_t)s * stride + (size_t)idx * 8);
#pragma unroll
        for (int j = 0; j < 8; ++j) a[j] += (float)v[j];
    }
    out[idx * 2]     = (float4){a[0], a[1], a[2], a[3]};
    out[idx * 2 + 1] = (float4){a[4], a[5], a[6], a[7]};
}

extern "C" void kernel_launch(void* const* d_in, const int* in_sizes, int n_in,
                              void* d_out, int out_size, void* d_ws, size_t ws_size,
                              hipStream_t stream) {
    (void)in_sizes; (void)n_in; (void)out_size; (void)ws_size;
    const float* x      = (const float*)d_in[0];
    const float* grid   = (const float*)d_in[1];
    const float* weight = (const float*)d_in[2];
    const float* bias   = (const float*)d_in[3];

    char* ws = (char*)d_ws;
    short*    wbf  = (short*)(ws + WOFF_WBF);
    short*    acts = (short*)(ws + WOFF_ACTS);
    _Float16* part = (_Float16*)(ws + WOFF_PART);

    prep2<<<WCAST_BLOCKS + (BATCH * IN_DIM / 4) / 256, 256, 0, stream>>>(
        weight, wbf, x, grid, acts);
    gemm_kan<<<128 * SPLITK, 256, 0, stream>>>(acts, wbf, part);
    reduce_out<<<(BATCH * OUT_DIM / 8) / 256, 256, 0, stream>>>(
        part, (const float4*)bias, (float4*)d_out);
}

// Round 11
// 51.753 us; speedup vs baseline: 2.3180x; 1.1041x over previous
//
#include <hip/hip_runtime.h>
#include <hip/hip_bf16.h>

#define IN_DIM  512
#define OUT_DIM 512
#define BATCH   4096
#define KDIM    4608            // permuted: k' = i*8+j (j=0..7 splines), 4096+i = silu
#define SPLITK  4
#define KSPLIT  1152            // KDIM / SPLITK
#define NSTEPS  18              // KSPLIT / 64

// ws layout (bytes)
#define WOFF_WBF  0
#define WSZ_WBF   (OUT_DIM * KDIM * 2)                  // 4,718,592 (permuted bf16 W)
#define WOFF_ACTS (WOFF_WBF + WSZ_WBF)
#define WSZ_ACTS  (BATCH * KDIM * 2)                    // 37,748,736 (permuted bf16 acts)
#define WOFF_PART (WOFF_ACTS + WSZ_ACTS)
#define WSZ_PART  (SPLITK * BATCH * OUT_DIM * 2)        // 16,777,216 (fp16 partials)

typedef __attribute__((ext_vector_type(8))) short bf16x8;
typedef __attribute__((ext_vector_type(4))) float f32x4;
typedef __attribute__((ext_vector_type(8))) _Float16 h16x8;

__device__ __forceinline__ unsigned long long pack4(float a, float b, float c, float d) {
    __hip_bfloat16 ha = __float2bfloat16(a), hb = __float2bfloat16(b),
                   hc = __float2bfloat16(c), hd = __float2bfloat16(d);
    return  (unsigned long long)*reinterpret_cast<unsigned short*>(&ha)
         | ((unsigned long long)*reinterpret_cast<unsigned short*>(&hb) << 16)
         | ((unsigned long long)*reinterpret_cast<unsigned short*>(&hc) << 32)
         | ((unsigned long long)*reinterpret_cast<unsigned short*>(&hd) << 48);
}

__device__ __forceinline__ float silux(float z) {     // silu(z)*z
    return z * z / (1.0f + __expf(-z));
}

// one spline eval -> 8-basis bf16 fragment, x-premultiplied (bases mi..mi+3
// nonzero, placed by 128-bit funnel shift; math verified rounds 4-10)
__device__ __forceinline__ bf16x8 spline_frag(float xv, float2 t) {
    float ss = (xv - t.x) * t.y;                      // in [0,5)
    int mi = (int)ss; mi = mi < 0 ? 0 : (mi > 4 ? 4 : mi);
    float u  = ss - (float)mi;
    float u2 = u * u, u3 = u2 * u;
    float om = 1.0f - u;
    float xb = xv * (1.0f / 6.0f);
    float b0 = om * om * om * xb;
    float b1 = (3.0f * u3 - 6.0f * u2 + 4.0f) * xb;
    float b2 = (-3.0f * u3 + 3.0f * u2 + 3.0f * u + 1.0f) * xb;
    float b3 = u3 * xb;
    unsigned long long p = pack4(b0, b1, b2, b3);
    unsigned sh = (unsigned)mi << 4;                  // 0,16,32,48,64
    unsigned long long l1 = p << (sh & 63);
    unsigned long long r1 = p >> ((64u - sh) & 63);
    unsigned long long lo = (sh == 64u) ? 0ull : l1;
    unsigned long long hi = (sh == 0u)  ? 0ull : ((sh == 64u) ? p : r1);
    union { unsigned long long q[2]; bf16x8 f; } u_;
    u_.q[0] = lo; u_.q[1] = hi;
    return u_.f;
}

// ---------------- K1: fused W cast+permute AND permuted-acts build ----------
// blocks [0,1024): wp[o][i*8+j] = bf16(w[o][j*512+i]), wp[o][4096+i] = bf16(w[o][8*512+i])
// blocks [1024,3072): acts[b][i*8+j] (16B stores) + acts[b][4096+i] (8B stores)
#define WCAST_BLOCKS 1024
__global__ __launch_bounds__(256) void prep2(const float* __restrict__ w,
                                             short* __restrict__ wp,
                                             const float* __restrict__ x,
                                             const float* __restrict__ grid,
                                             short* __restrict__ acts) {
    int blk = blockIdx.x;
    if (blk < WCAST_BLOCKS) {
        int idx = blk * 256 + threadIdx.x;              // (o,i)
        int o = idx >> 9;
        int i = idx & 511;
        const float* wo = w + (size_t)o * KDIM;
        bf16x8 v;
#pragma unroll
        for (int j = 0; j < 8; ++j) {
            __hip_bfloat16 h = __float2bfloat16(wo[j * 512 + i]);
            v[j] = *reinterpret_cast<short*>(&h);
        }
        *reinterpret_cast<bf16x8*>(wp + (size_t)o * KDIM + i * 8) = v;
        __hip_bfloat16 h8 = __float2bfloat16(wo[8 * 512 + i]);
        wp[(size_t)o * KDIM + 4096 + i] = *reinterpret_cast<short*>(&h8);
        return;
    }
    int idx = (blk - WCAST_BLOCKS) * 256 + threadIdx.x; // 0..524287; 4 i's each
    int b  = idx >> 7;
    int i0 = (idx & 127) * 4;
    float4 xv = *reinterpret_cast<const float4*>(&x[(size_t)b * IN_DIM + i0]);
    short* arow = acts + (size_t)b * KDIM;
    short4 sil;
#pragma unroll
    for (int c = 0; c < 4; ++c) {
        int i = i0 + c;
        float xc = (c == 0) ? xv.x : (c == 1) ? xv.y : (c == 2) ? xv.z : xv.w;
        float g0 = grid[i * 6];
        float g5 = grid[i * 6 + 5];
        float2 t = make_float2(g0, 5.0f / (g5 - g0));
        bf16x8 f = spline_frag(xc, t);
        *reinterpret_cast<bf16x8*>(&arow[i * 8]) = f;   // 16B coalesced
        __hip_bfloat16 hs = __float2bfloat16(silux(xc));
        ((short*)&sil)[c] = *reinterpret_cast<short*>(&hs);
    }
    *reinterpret_cast<short4*>(&arow[4096 + i0]) = sil; // 8B coalesced
}

// ---------------- K2: bf16 MFMA GEMM (m97 structure), split-K=4 -------------
// 256 thr = 4 waves (2x2), BM=BN=128, BK=64, grid 512 = 2 blocks/CU (R4 proven).
#define BM 128
#define BN 128
#define BK 64

__global__ __launch_bounds__(256) void gemm_kan(const short* __restrict__ A,
                                                const short* __restrict__ W,
                                                _Float16* __restrict__ part) {
    __shared__ __align__(16) short As[BM * BK];    // 16 KB, XOR-swizzled 16B slots
    __shared__ __align__(16) short Ws[BN * BK];    // 16 KB

    // XCD swizzle (bijective: 512 = 8*64); bn-minor so 4 consecutive blocks
    // share an A-panel within one XCD's L2 (R4's proven mapping).
    int l  = (blockIdx.x & 7) * 64 + (blockIdx.x >> 3);
    int sk = l >> 7;              // 0..3
    int mn = l & 127;
    int bm = mn >> 2;             // 0..31
    int bn = mn & 3;              // 0..3

    int tid  = threadIdx.x;
    int lane = tid & 63;
    int wid  = tid >> 6;          // 0..3
    int wr   = wid >> 1;          // 0..1
    int wc   = wid & 1;           // 0..1

    const short* Ab = A + (size_t)(bm * BM) * KDIM + sk * KSPLIT;
    const short* Wb = W + (size_t)(bn * BN) * KDIM + sk * KSPLIT;

    f32x4 acc[4][4];
#pragma unroll
    for (int m = 0; m < 4; ++m)
#pragma unroll
        for (int n = 0; n < 4; ++n) acc[m][n] = (f32x4){0.f, 0.f, 0.f, 0.f};

    // staging: wave w covers rows r0+srow, slot lane&7; LDS slot s of row r
    // holds global col8 (s ^ (r&7)) -> source col8 = (lane&7) ^ srow (rule #21)
    int srow = lane >> 3;
    int scol = ((lane & 7) ^ srow) * 8;

    for (int kb = 0; kb < NSTEPS; ++kb) {
        int k0 = kb * BK;
        __syncthreads();
#pragma unroll
        for (int i = 0; i < 4; ++i) {           // A tile: 128 rows
            int r0 = i * 32 + wid * 8;
            __builtin_amdgcn_global_load_lds(
                (const __attribute__((address_space(1))) void*)(Ab + (size_t)(r0 + srow) * KDIM + k0 + scol),
                (__attribute__((address_space(3))) void*)(&As[r0 * 64]),
                16, 0, 0);
        }
#pragma unroll
        for (int i = 0; i < 4; ++i) {           // W tile: 128 rows
            int r0 = i * 32 + wid * 8;
            __builtin_amdgcn_global_load_lds(
                (const __attribute__((address_space(1))) void*)(Wb + (size_t)(r0 + srow) * KDIM + k0 + scol),
                (__attribute__((address_space(3))) void*)(&Ws[r0 * 64]),
                16, 0, 0);
        }
        __syncthreads();

        int g = lane >> 4;
        int fr = lane & 15;
#pragma unroll
        for (int ks = 0; ks < 2; ++ks) {
            int kk8 = ks * 4 + g;
            bf16x8 af[4], wf[4];
#pragma unroll
            for (int m = 0; m < 4; ++m) {
                int row = wr * 64 + m * 16 + fr;
                int slot = kk8 ^ (row & 7);
                af[m] = *reinterpret_cast<const bf16x8*>(&As[row * 64 + slot * 8]);
            }
#pragma unroll
            for (int n = 0; n < 4; ++n) {
                int col = wc * 64 + n * 16 + fr;
                int slot = kk8 ^ (col & 7);
                wf[n] = *reinterpret_cast<const bf16x8*>(&Ws[col * 64 + slot * 8]);
            }
#pragma unroll
            for (int m = 0; m < 4; ++m)
#pragma unroll
                for (int n = 0; n < 4; ++n)
                    acc[m][n] = __builtin_amdgcn_mfma_f32_16x16x32_bf16(af[m], wf[n], acc[m][n], 0, 0, 0);
        }
    }

    // epilogue: C/D col = lane&15, row = (lane>>4)*4 + reg; fp16 partials
    _Float16* p = part + (size_t)sk * BATCH * OUT_DIM;
    int crow0 = bm * BM + wr * 64 + (lane >> 4) * 4;
    int ccol0 = bn * BN + wc * 64 + (lane & 15);
#pragma unroll
    for (int m = 0; m < 4; ++m)
#pragma unroll
        for (int n = 0; n < 4; ++n)
#pragma unroll
            for (int r = 0; r < 4; ++r)
                p[(size_t)(crow0 + m * 16 + r) * OUT_DIM + ccol0 + n * 16] =
                    (_Float16)acc[m][n][r];
}

// ---------------- K3: reduce fp16 partials + bias ----------------
__global__ __launch_bounds__(256) void reduce_out(const _Float16* __restrict__ part,
                                                  const float4* __restrict__ bias,
                                                  float4* __restrict__ out) {
    int idx = blockIdx.x * 256 + threadIdx.x;     // 8 outputs each
    const size_t stride = (size_t)BATCH * OUT_DIM;
    float4 b0 = bias[(idx & 63) * 2];
    float4 b1 = bias[(idx & 63) * 2 + 1];
    float a[8] = {b0.x, b0.y, b0.z, b0.w, b1.x, b1.y, b1.z, b1.w};
#pragma unroll
    for (int s = 0; s < SPLITK; ++s) {
        h16x8 v = *reinterpret_cast<const h16x8*>(part + (size_t)s * stride + (size_t)idx * 8);
#pragma unroll
        for (int j = 0; j < 8; ++j) a[j] += (float)v[j];
    }
    out[idx * 2]     = (float4){a[0], a[1], a[2], a[3]};
    out[idx * 2 + 1] = (float4){a[4], a[5], a[6], a[7]};
}

extern "C" void kernel_launch(void* const* d_in, const int* in_sizes, int n_in,
                              void* d_out, int out_size, void* d_ws, size_t ws_size,
                              hipStream_t stream) {
    (void)in_sizes; (void)n_in; (void)out_size; (void)ws_size;
    const float* x      = (const float*)d_in[0];
    const float* grid   = (const float*)d_in[1];
    const float* weight = (const float*)d_in[2];
    const float* bias   = (const float*)d_in[3];

    char* ws = (char*)d_ws;
    short*    wbf  = (short*)(ws + WOFF_WBF);
    short*    acts = (short*)(ws + WOFF_ACTS);
    _Float16* part = (_Float16*)(ws + WOFF_PART);

    prep2<<<WCAST_BLOCKS + (BATCH * IN_DIM / 4) / 256, 256, 0, stream>>>(
        weight, wbf, x, grid, acts);
    gemm_kan<<<128 * SPLITK, 256, 0, stream>>>(acts, wbf, part);
    reduce_out<<<(BATCH * OUT_DIM / 8) / 256, 256, 0, stream>>>(
        part, (const float4*)bias, (float4*)d_out);
}

// Round 12
// 47.931 us; speedup vs baseline: 2.5028x; 1.0797x over previous
//
#include <hip/hip_runtime.h>
#include <hip/hip_bf16.h>

#define IN_DIM  512
#define OUT_DIM 512
#define BATCH   4096
#define NBASIS  9
#define KDIM    (IN_DIM * NBASIS)     // 4608, natural order k = j*512 + i
#define SPLITK  4
#define KSPLIT  1152
#define NSTEPS  18                    // KSPLIT / 64

// ws layout (bytes) — identical to round 4
#define WOFF_WBF  0
#define WSZ_WBF   (OUT_DIM * KDIM * 2)            // 4,718,592
#define WOFF_ACTS (WOFF_WBF + WSZ_WBF)
#define WSZ_ACTS  (BATCH * KDIM * 2)              // 37,748,736
#define WOFF_PART (WOFF_ACTS + WSZ_ACTS)
#define WSZ_PART  (SPLITK * BATCH * OUT_DIM * 2)  // 16,777,216 (fp16)

typedef __attribute__((ext_vector_type(8))) short bf16x8;
typedef __attribute__((ext_vector_type(4))) float f32x4;
typedef __attribute__((ext_vector_type(8))) _Float16 h16x8;

#define NW_BLOCKS 2304   // weight-cast blocks: 589824 float4 / 256

// ---------------- K1: fused weight cast + acts build (R4 verbatim) ----------
__global__ __launch_bounds__(256) void prep(const float4* __restrict__ w,
                                            short* __restrict__ wb,
                                            const float* __restrict__ x,
                                            const float* __restrict__ grid,
                                            __hip_bfloat16* __restrict__ acts) {
    int blk = blockIdx.x;
    if (blk < NW_BLOCKS) {
        int idx = blk * 256 + threadIdx.x;             // 589824 float4s
        float4 v = w[idx];
        __hip_bfloat16 h[4] = {__float2bfloat16(v.x), __float2bfloat16(v.y),
                               __float2bfloat16(v.z), __float2bfloat16(v.w)};
        *reinterpret_cast<short4*>(wb + (size_t)idx * 4) = *reinterpret_cast<short4*>(h);
        return;
    }
    int idx = (blk - NW_BLOCKS) * 256 + threadIdx.x;   // 0 .. 4096*512-1
    int b = idx >> 9;
    int i = idx & 511;
    float xv = x[idx];
    float g0 = grid[i * 6];
    float g5 = grid[i * 6 + 5];
    float s = (xv - g0) * (5.0f / (g5 - g0));
    int mi = (int)s;
    mi = mi < 0 ? 0 : (mi > 4 ? 4 : mi);
    float u = s - (float)mi;
    float u2 = u * u, u3 = u2 * u;
    const float c6 = 1.0f / 6.0f;
    float om = 1.0f - u;
    float b0 = om * om * om * c6;
    float b1 = (3.0f * u3 - 6.0f * u2 + 4.0f) * c6;
    float b2 = (-3.0f * u3 + 3.0f * u2 + 3.0f * u + 1.0f) * c6;
    float b3 = u3 * c6;
    float sil = xv / (1.0f + __expf(-xv));

    __hip_bfloat16* dst = acts + (size_t)b * KDIM + i;
#pragma unroll
    for (int j = 0; j < 8; ++j) {
        int r = j - mi;
        float v = (r == 0) ? b0 : (r == 1) ? b1 : (r == 2) ? b2 : (r == 3) ? b3 : 0.0f;
        dst[j * IN_DIM] = __float2bfloat16(v * xv);
    }
    dst[8 * IN_DIM] = __float2bfloat16(sil * xv);
}

// ---------------- K2: bf16 MFMA GEMM, T3-min pipelined double-buffer --------
// 256 thr = 4 waves (2x2), BM=BN=128, BK=64, split-K=4, grid 512 = 2 blocks/CU.
// Per tile: 8 global_load_lds per wave (4 A + 4 W). Loop: plain s_barrier ->
// issue tile t+1 into buf^1 -> s_waitcnt vmcnt(8)+s_barrier (tile t landed,
// t+1's 8 stay in flight) -> ds_read+MFMA on buf. Never drains to 0 mid-loop.
#define BM 128
#define BN 128
#define BK 64

__global__ __launch_bounds__(256) void gemm_kan(const short* __restrict__ A,
                                                const short* __restrict__ W,
                                                _Float16* __restrict__ part) {
    __shared__ __align__(16) short As[2][BM * BK];    // 2 x 16 KB
    __shared__ __align__(16) short Ws[2][BN * BK];    // 2 x 16 KB

    // XCD swizzle (bijective: 512 = 8*64) — R4's proven mapping
    int bid = (blockIdx.x & 7) * 64 + (blockIdx.x >> 3);
    int sk = bid >> 7;            // 0..3
    int mn = bid & 127;
    int bm = mn >> 2;             // 0..31
    int bn = mn & 3;              // 0..3

    int tid  = threadIdx.x;
    int lane = tid & 63;
    int wid  = tid >> 6;          // 0..3
    int wr   = wid >> 1;          // 0..1
    int wc   = wid & 1;           // 0..1

    const short* Ab = A + (size_t)(bm * BM) * KDIM + sk * KSPLIT;
    const short* Wb = W + (size_t)(bn * BN) * KDIM + sk * KSPLIT;

    f32x4 acc[4][4];
#pragma unroll
    for (int m = 0; m < 4; ++m)
#pragma unroll
        for (int n = 0; n < 4; ++n) acc[m][n] = (f32x4){0.f, 0.f, 0.f, 0.f};

    // staging: LDS slot s of row r holds global col8 (s ^ (r&7));
    // source col8 = (lane&7) ^ (lane>>3)  (rule #21 both-sides swizzle)
    int srow = lane >> 3;
    int scol = ((lane & 7) ^ srow) * 8;

    auto stage = [&](int kb, int buf) {
        int k0 = kb * BK;
#pragma unroll
        for (int i = 0; i < 4; ++i) {            // A: 128 rows
            int r0 = i * 32 + wid * 8;
            __builtin_amdgcn_global_load_lds(
                (const __attribute__((address_space(1))) void*)(Ab + (size_t)(r0 + srow) * KDIM + k0 + scol),
                (__attribute__((address_space(3))) void*)(&As[buf][r0 * 64]),
                16, 0, 0);
        }
#pragma unroll
        for (int i = 0; i < 4; ++i) {            // W: 128 rows
            int r0 = i * 32 + wid * 8;
            __builtin_amdgcn_global_load_lds(
                (const __attribute__((address_space(1))) void*)(Wb + (size_t)(r0 + srow) * KDIM + k0 + scol),
                (__attribute__((address_space(3))) void*)(&Ws[buf][r0 * 64]),
                16, 0, 0);
        }
    };

    stage(0, 0);                                 // prologue: 8 in flight

    int g  = lane >> 4;
    int fr = lane & 15;
    for (int kb = 0; kb < NSTEPS; ++kb) {
        int cur = kb & 1;
        // all waves done reading buf[cur^1] (previous compute phase)
        __builtin_amdgcn_sched_barrier(0);
        asm volatile("s_barrier" ::: "memory");
        if (kb + 1 < NSTEPS) {
            stage(kb + 1, cur ^ 1);              // issue next; DO NOT drain it
            asm volatile("s_waitcnt vmcnt(8)\n\ts_barrier" ::: "memory");
        } else {
            asm volatile("s_waitcnt vmcnt(0)\n\ts_barrier" ::: "memory");
        }
        __builtin_amdgcn_sched_barrier(0);

        const short* Ac = &As[cur][0];
        const short* Wc = &Ws[cur][0];
#pragma unroll
        for (int ks = 0; ks < 2; ++ks) {
            int kk8 = ks * 4 + g;
            bf16x8 af[4], wf[4];
#pragma unroll
            for (int m = 0; m < 4; ++m) {
                int row = wr * 64 + m * 16 + fr;
                int slot = kk8 ^ (row & 7);
                af[m] = *reinterpret_cast<const bf16x8*>(&Ac[row * 64 + slot * 8]);
            }
#pragma unroll
            for (int n = 0; n < 4; ++n) {
                int col = wc * 64 + n * 16 + fr;
                int slot = kk8 ^ (col & 7);
                wf[n] = *reinterpret_cast<const bf16x8*>(&Wc[col * 64 + slot * 8]);
            }
#pragma unroll
            for (int m = 0; m < 4; ++m)
#pragma unroll
                for (int n = 0; n < 4; ++n)
                    acc[m][n] = __builtin_amdgcn_mfma_f32_16x16x32_bf16(af[m], wf[n], acc[m][n], 0, 0, 0);
        }
    }

    // epilogue: C/D col = lane&15, row = (lane>>4)*4 + reg; fp16 partials
    _Float16* p = part + (size_t)sk * BATCH * OUT_DIM;
    int crow0 = bm * BM + wr * 64 + (lane >> 4) * 4;
    int ccol0 = bn * BN + wc * 64 + (lane & 15);
#pragma unroll
    for (int m = 0; m < 4; ++m)
#pragma unroll
        for (int n = 0; n < 4; ++n)
#pragma unroll
            for (int r = 0; r < 4; ++r)
                p[(size_t)(crow0 + m * 16 + r) * OUT_DIM + ccol0 + n * 16] =
                    (_Float16)acc[m][n][r];
}

// ---------------- K3: reduce fp16 partials + bias (R4 verbatim) -------------
__global__ __launch_bounds__(256) void reduce_out(const _Float16* __restrict__ part,
                                                  const float4* __restrict__ bias,
                                                  float4* __restrict__ out) {
    int idx = blockIdx.x * 256 + threadIdx.x;     // 8 outputs each
    const size_t stride = (size_t)BATCH * OUT_DIM;
    float4 b0 = bias[(idx & 63) * 2];
    float4 b1 = bias[(idx & 63) * 2 + 1];
    float a[8] = {b0.x, b0.y, b0.z, b0.w, b1.x, b1.y, b1.z, b1.w};
#pragma unroll
    for (int s = 0; s < SPLITK; ++s) {
        h16x8 v = *reinterpret_cast<const h16x8*>(part + (size_t)s * stride + (size_t)idx * 8);
#pragma unroll
        for (int j = 0; j < 8; ++j) a[j] += (float)v[j];
    }
    out[idx * 2]     = (float4){a[0], a[1], a[2], a[3]};
    out[idx * 2 + 1] = (float4){a[4], a[5], a[6], a[7]};
}

extern "C" void kernel_launch(void* const* d_in, const int* in_sizes, int n_in,
                              void* d_out, int out_size, void* d_ws, size_t ws_size,
                              hipStream_t stream) {
    (void)in_sizes; (void)n_in; (void)out_size; (void)ws_size;
    const float* x      = (const float*)d_in[0];
    const float* grid   = (const float*)d_in[1];
    const float* weight = (const float*)d_in[2];
    const float* bias   = (const float*)d_in[3];

    char* ws = (char*)d_ws;
    short*          wbf  = (short*)(ws + WOFF_WBF);
    __hip_bfloat16* acts = (__hip_bfloat16*)(ws + WOFF_ACTS);
    _Float16*       part = (_Float16*)(ws + WOFF_PART);

    prep<<<NW_BLOCKS + (BATCH * IN_DIM) / 256, 256, 0, stream>>>(
        (const float4*)weight, wbf, x, grid, acts);
    gemm_kan<<<128 * SPLITK, 256, 0, stream>>>((const short*)acts, wbf, part);
    reduce_out<<<(BATCH * OUT_DIM / 8) / 256, 256, 0, stream>>>(
        part, (const float4*)bias, (float4*)d_out);
}